// Round 15
// baseline (593.192 us; speedup 1.0000x reference)
//
#include <hip/hip_runtime.h>
#include <hip/hip_bf16.h>
#include <cstdint>

#define N_NODES 8192
#define DDIM    64
#define DX      128
#define NEDGE   262144
#define BR      256                       // query rows per block (16 waves, 32x32 MFMA tiles)
#define BC      64                        // key/value columns per tile
#define SPLITS  16                        // grid 32x16=512 = 2 blocks/CU = 32 waves/CU (max)
#define TILES   (N_NODES / BC / SPLITS)   // 8 (compile-time)
#define RCAP    64                        // per-row edge bin capacity (Poisson(32), 5.7 sigma)
#define MSHIFT  66.0f                     // fixed softmax shift: scores < 64 always

typedef float f32x16 __attribute__((ext_vector_type(16)));
typedef short short8 __attribute__((ext_vector_type(8)));

__device__ __forceinline__ short f2bf(float f) {
    union { float f; uint32_t u; } v; v.f = f;
    uint32_t u = v.u;
    uint32_t r = (u + 0x7FFFu + ((u >> 16) & 1u)) >> 16;
    return (short)r;
}
__device__ __forceinline__ float bf2f(short s) {
    union { uint32_t u; float f; } v;
    v.u = ((uint32_t)(uint16_t)s) << 16;
    return v.f;
}

// ---- fused prep: [0,2048) X-build, [2048,2304) Y-transpose, [2304,3328) edges
__global__ void cpa_prep_all(const float* __restrict__ mag, const float* __restrict__ phase,
                             const int* __restrict__ ei, const float* __restrict__ ea,
                             const float* __restrict__ W, const float* __restrict__ b,
                             short* __restrict__ Xbf, short* __restrict__ Ybt,
                             float* __restrict__ es, int* __restrict__ cnt,
                             int* __restrict__ keys) {
    __shared__ short tile[64][65];
    __shared__ float wsb[5];
    const int blk = blockIdx.x;
    const int tid = threadIdx.x;
    if (blk < 2048) {
        int idx = blk * 256 + tid;                 // N*64 threads
        int i = idx >> 6, d = idx & 63;
        float m = mag[idx], p = phase[idx];
        Xbf[i * DX + d]      = f2bf(m * __cosf(p));
        Xbf[i * DX + 64 + d] = f2bf(m * __sinf(p));
    } else if (blk < 2304) {
        int bb = blk - 2048;
        int bi = bb >> 1;
        int bc = bb & 1;
        int i0 = bi * 64;
        const float* src = bc ? phase : mag;
        for (int itr = 0; itr < 16; ++itr) {
            int idx = tid + itr * 256;             // 0..4095
            int ii = idx >> 6, cc = idx & 63;
            tile[ii][cc] = f2bf(src[(size_t)(i0 + ii) * 64 + cc]);
        }
        __syncthreads();
        for (int itr = 0; itr < 16; ++itr) {
            int idx = tid + itr * 256;
            int cc = idx >> 6, ii = idx & 63;
            Ybt[(size_t)(bc * 64 + cc) * N_NODES + i0 + ii] = tile[ii][cc];
        }
    } else {
        if (tid < 64) {
            float w0 = W[tid * 4 + 0], w1 = W[tid * 4 + 1];
            float w2 = W[tid * 4 + 2], w3 = W[tid * 4 + 3];
            float bb = b[tid];
            #pragma unroll
            for (int o = 32; o > 0; o >>= 1) {
                w0 += __shfl_down(w0, o);
                w1 += __shfl_down(w1, o);
                w2 += __shfl_down(w2, o);
                w3 += __shfl_down(w3, o);
                bb += __shfl_down(bb, o);
            }
            if (tid == 0) { wsb[0] = w0; wsb[1] = w1; wsb[2] = w2; wsb[3] = w3; wsb[4] = bb; }
        }
        __syncthreads();
        int e = (blk - 2304) * 256 + tid;
        float4 a = *(const float4*)(ea + (size_t)e * 4);
        es[e] = a.x * wsb[0] + a.y * wsb[1] + a.z * wsb[2] + a.w * wsb[3] + wsb[4];
        int src = ei[e];
        int dst = ei[NEDGE + e];
        int pos = atomicAdd(&cnt[src], 1);
        if (pos < RCAP) keys[src * RCAP + pos] = (dst << 18) | e;
    }
}

// ---- per-row sort by (dst,e): one wave per row, 1 key/lane, 64-wide bitonic;
// mark all-but-last duplicate dst dead (numpy last-wins).
__global__ __launch_bounds__(256) void cpa_sortrows(const int* __restrict__ cnt,
                                                    int* __restrict__ keys) {
    int row  = blockIdx.x * 4 + (threadIdx.x >> 6);
    int lane = threadIdx.x & 63;
    int len  = min(cnt[row], RCAP);
    int base = row * RCAP;
    int v = (lane < len) ? keys[base + lane] : 0x7FFFFFFF;

    #pragma unroll
    for (int k = 2; k <= 64; k <<= 1) {
        #pragma unroll
        for (int j = k >> 1; j >= 1; j >>= 1) {
            int p = __shfl_xor(v, j);
            bool asc = (lane & k) == 0;
            bool low = (lane & j) == 0;
            v = (low == asc) ? min(v, p) : max(v, p);
        }
    }
    int nxt = __shfl_down(v, 1);
    bool dead = (lane + 1 < len) && ((v >> 18) == (nxt >> 18));
    if (lane < len) keys[base + lane] = v | (dead ? 0x80000000 : 0);
}

// ---- flash attention, 32x32x16 MFMA core (R13 inner loop), 1024-thread blocks:
// BR=256 rows / 16 waves; LDS 72.7 KB -> 2 blocks/CU = 32 waves/CU (HW max).
// Staging amortized over 2x rows vs R13. Wave w: rg=w>>1 (0..7), cg=w&1.
__global__ __launch_bounds__(1024, 8) void cpa_flash(
    const short* __restrict__ Xbf, const short* __restrict__ Ybt,
    const float* __restrict__ es, const int* __restrict__ keys,
    const int* __restrict__ cnt,
    float* __restrict__ lsplit, short* __restrict__ Opart)
{
    __shared__ short Xj[BC][136];     // X tile (j rows), stride 136          (17.4 KB)
    __shared__ short Yt[DX][72];      // V tile K-transposed                  (18.4 KB)
    __shared__ short Pl[BR][72];      // P tile, wave-private 32x32 regions   (36.9 KB)

    const int tid  = threadIdx.x;
    const int lane = tid & 63;
    const int w    = tid >> 6;        // wave 0..15
    const int l31  = lane & 31;
    const int lh   = lane >> 5;       // K-half within fragment
    const int rg   = w >> 1;          // row group (32 rows), S and PV
    const int cg   = w & 1;           // S col group / P region half
    const int ocg0 = (w & 1) * 2;     // PV col-tile pair {ocg0, ocg0+1}

    const int ib = blockIdx.x;        // 0..31
    const int split = blockIdx.y;     // 0..SPLITS-1
    const int i0 = ib * BR;
    const int jstart = split * (N_NODES / SPLITS);

    // Xi A-fragments: rows rg*32+l31, 8 K-chunks of 16 over 128 features (global, once)
    short8 afrag[8];
    #pragma unroll
    for (int kf = 0; kf < 8; ++kf)
        afrag[kf] = *(const short8*)(Xbf + (size_t)(i0 + rg * 32 + l31) * DX + kf * 16 + lh * 8);

    short8 ones;
    #pragma unroll
    for (int j = 0; j < 8; ++j) ones[j] = (short)0x3F80;   // bf16 1.0

    // walker cursor: lane<32 owns row i0 + rg*32 + lane (both cg waves walk, apply own half)
    int cur = 0, rend = 0;
    if (lane < 32) {
        int i = i0 + rg * 32 + l31;
        cur = i * RCAP;
        rend = cur + min(cnt[i], RCAP);
        while (cur < rend) {
            int k = keys[cur];
            if (((k >> 18) & 0x1FFF) >= jstart) break;
            ++cur;
        }
    }

    f32x16 O0, O1, lC;
    #pragma unroll
    for (int r = 0; r < 16; ++r) { O0[r] = 0.f; O1[r] = 0.f; lC[r] = 0.f; }

    for (int tt = 0; tt < TILES; ++tt) {
        const int j0 = jstart + tt * BC;
        // phase A: stage X_j and Y_t tiles (1024 threads: one pass each)
        {
            int r = tid >> 4;                     // 0..63
            int c8 = (tid & 15) << 3;
            *(int4*)(&Xj[r][c8]) = *(const int4*)(Xbf + (size_t)(j0 + r) * DX + c8);
            int n = tid >> 3;                     // 0..127
            int k8 = (tid & 7) << 3;
            *(int4*)(&Yt[n][k8]) = *(const int4*)(Ybt + (size_t)n * N_NODES + j0 + k8);
        }
        __syncthreads();  // B1: staging visible

        // phase B: S (32x32) = Xi(rg) · Xj(cg)^T, 8 K-steps
        f32x16 S;
        #pragma unroll
        for (int r = 0; r < 16; ++r) S[r] = 0.f;
        #pragma unroll
        for (int kf = 0; kf < 8; ++kf) {
            short8 bfrag = *(const short8*)&Xj[cg * 32 + l31][kf * 16 + lh * 8];
            S = __builtin_amdgcn_mfma_f32_32x32x16_bf16(afrag[kf], bfrag, S, 0, 0, 0);
        }
        // p = exp(S - 66) -> own Pl region (row rg*32+rowl, col cg*32+l31)
        #pragma unroll
        for (int r = 0; r < 16; ++r) {
            int rowl = 4 * lh + (r & 3) + 8 * (r >> 2);
            Pl[rg * 32 + rowl][cg * 32 + l31] = f2bf(__expf(S[r] - MSHIFT));
        }
        // bias RMW on own region (same-wave DS ordering; lanes 0..31)
        if (lane < 32) {
            const int jend = j0 + BC;
            const int wlo = j0 + cg * 32;
            int c = cur;
            while (c < rend) {
                int k = keys[c];
                int dst = (k >> 18) & 0x1FFF;
                if (dst >= jend) break;
                ++c;
                if (k >= 0) {
                    unsigned cl = (unsigned)(dst - wlo);
                    if (cl < 32u) {
                        short* p = &Pl[rg * 32 + l31][cg * 32 + (int)cl];
                        *p = f2bf(bf2f(*p) * __expf(es[k & 0x3FFFF]));
                    }
                }
            }
            cur = c;
        }
        __syncthreads();  // B2: biased P visible to all waves

        // phase D: O += P·Y (2 col tiles sharing A-frags); l += P·1 (even waves)
        #pragma unroll
        for (int ks = 0; ks < 4; ++ks) {
            short8 pa  = *(const short8*)&Pl[rg * 32 + l31][ks * 16 + lh * 8];
            short8 yb0 = *(const short8*)&Yt[ocg0 * 32 + l31][ks * 16 + lh * 8];
            short8 yb1 = *(const short8*)&Yt[(ocg0 + 1) * 32 + l31][ks * 16 + lh * 8];
            O0 = __builtin_amdgcn_mfma_f32_32x32x16_bf16(pa, yb0, O0, 0, 0, 0);
            O1 = __builtin_amdgcn_mfma_f32_32x32x16_bf16(pa, yb1, O1, 0, 0, 0);
            if (!(w & 1))
                lC = __builtin_amdgcn_mfma_f32_32x32x16_bf16(pa, ones, lC, 0, 0, 0);
        }
        __syncthreads();  // B4: WAR before next staging / P-store
    }

    // epilogue: O (bf16) and l (fixed shift => merge is a plain sum)
    #pragma unroll
    for (int r = 0; r < 16; ++r) {
        int row = rg * 32 + 4 * lh + (r & 3) + 8 * (r >> 2);
        size_t base = ((size_t)split * N_NODES + i0 + row) * DX;
        Opart[base + ocg0 * 32 + l31]       = f2bf(O0[r]);
        Opart[base + (ocg0 + 1) * 32 + l31] = f2bf(O1[r]);
    }
    if (!(w & 1) && l31 == 0) {
        #pragma unroll
        for (int r = 0; r < 16; ++r) {
            int row = rg * 32 + 4 * lh + (r & 3) + 8 * (r >> 2);
            lsplit[(size_t)split * N_NODES + i0 + row] = lC[r];
        }
    }
}

// ---- merge splits (plain sums) + normalize + write [new_mag | new_phase]
__global__ void cpa_merge(const float* __restrict__ lsplit, const short* __restrict__ Opart,
                          float* __restrict__ out) {
    int gid = blockIdx.x * 256 + threadIdx.x;   // N*128 threads
    int i = gid >> 7;
    int c = gid & 127;
    float den = 0.f, num = 0.f;
    #pragma unroll
    for (int s = 0; s < SPLITS; ++s) {
        den += lsplit[(size_t)s * N_NODES + i];
        num += bf2f(Opart[((size_t)s * N_NODES + i) * DX + c]);
    }
    float val = num / den;
    if (c < 64) out[(size_t)i * 64 + c] = val;
    else        out[(size_t)N_NODES * 64 + (size_t)i * 64 + (c - 64)] = val;
}

extern "C" void kernel_launch(void* const* d_in, const int* in_sizes, int n_in,
                              void* d_out, int out_size, void* d_ws, size_t ws_size,
                              hipStream_t stream)
{
    const float* mag   = (const float*)d_in[0];
    const float* phase = (const float*)d_in[1];
    const int*   ei    = (const int*)d_in[2];     // edge_index [2][E] (int32 per harness)
    const float* ea    = (const float*)d_in[3];
    const float* W     = (const float*)d_in[4];
    const float* b     = (const float*)d_in[5];
    float* out = (float*)d_out;

    char* ws = (char*)d_ws;
    short* Xbf    = (short*)(ws + 0);               // 2 MB
    short* Ybt    = (short*)(ws + 2097152);         // 2 MB
    float* es     = (float*)(ws + 4194304);         // 1 MB
    int*   keys   = (int*)  (ws + 5242880);         // 2 MB (8192 rows x 64 bins)
    int*   cnt    = (int*)  (ws + 7340032);         // 32 KB
    float* lsplit = (float*)(ws + 7372800);         // 512 KB (16 splits)
    short* Opart  = (short*)(ws + 7897088);         // 32 MB (bf16, 16 splits)

    hipMemsetAsync(cnt, 0, N_NODES * sizeof(int), stream);
    cpa_prep_all<<<2048 + 256 + NEDGE / 256, 256, 0, stream>>>(mag, phase, ei, ea, W, b,
                                                               Xbf, Ybt, es, cnt, keys);
    cpa_sortrows<<<N_NODES / 4, 256, 0, stream>>>(cnt, keys);
    cpa_flash<<<dim3(N_NODES / BR, SPLITS), 1024, 0, stream>>>(Xbf, Ybt, es, keys, cnt,
                                                               lsplit, Opart);
    cpa_merge<<<N_NODES * DX / 256, 256, 0, stream>>>(lsplit, Opart, out);
}

// Round 16
// 182.538 us; speedup vs baseline: 3.2497x; 3.2497x over previous
//
#include <hip/hip_runtime.h>
#include <hip/hip_bf16.h>
#include <cstdint>

#define N_NODES 8192
#define DDIM    64
#define DX      128
#define NEDGE   262144
#define BR      128                       // query rows per block (8 waves, 32x32 MFMA tiles)
#define BC      64                        // key/value columns per tile
#define SPLITS  8
#define TILES   (N_NODES / BC / SPLITS)   // 16 (compile-time)
#define RCAP    64                        // per-row edge bin capacity (Poisson(32), 5.7 sigma)
#define MSHIFT  66.0f                     // fixed softmax shift: scores < 64 always

typedef float f32x16 __attribute__((ext_vector_type(16)));
typedef short short8 __attribute__((ext_vector_type(8)));

__device__ __forceinline__ short f2bf(float f) {
    union { float f; uint32_t u; } v; v.f = f;
    uint32_t u = v.u;
    uint32_t r = (u + 0x7FFFu + ((u >> 16) & 1u)) >> 16;
    return (short)r;
}
__device__ __forceinline__ float bf2f(short s) {
    union { uint32_t u; float f; } v;
    v.u = ((uint32_t)(uint16_t)s) << 16;
    return v.f;
}

// ---- fused prep: [0,2048) X-build, [2048,2304) Y-transpose, [2304,3328) edges
__global__ void cpa_prep_all(const float* __restrict__ mag, const float* __restrict__ phase,
                             const int* __restrict__ ei, const float* __restrict__ ea,
                             const float* __restrict__ W, const float* __restrict__ b,
                             short* __restrict__ Xbf, short* __restrict__ Ybt,
                             float* __restrict__ es, int* __restrict__ cnt,
                             int* __restrict__ keys) {
    __shared__ short tile[64][65];
    __shared__ float wsb[5];
    const int blk = blockIdx.x;
    const int tid = threadIdx.x;
    if (blk < 2048) {
        int idx = blk * 256 + tid;                 // N*64 threads
        int i = idx >> 6, d = idx & 63;
        float m = mag[idx], p = phase[idx];
        Xbf[i * DX + d]      = f2bf(m * __cosf(p));
        Xbf[i * DX + 64 + d] = f2bf(m * __sinf(p));
    } else if (blk < 2304) {
        int bb = blk - 2048;
        int bi = bb >> 1;
        int bc = bb & 1;
        int i0 = bi * 64;
        const float* src = bc ? phase : mag;
        for (int itr = 0; itr < 16; ++itr) {
            int idx = tid + itr * 256;             // 0..4095
            int ii = idx >> 6, cc = idx & 63;
            tile[ii][cc] = f2bf(src[(size_t)(i0 + ii) * 64 + cc]);
        }
        __syncthreads();
        for (int itr = 0; itr < 16; ++itr) {
            int idx = tid + itr * 256;
            int cc = idx >> 6, ii = idx & 63;
            Ybt[(size_t)(bc * 64 + cc) * N_NODES + i0 + ii] = tile[ii][cc];
        }
    } else {
        if (tid < 64) {
            float w0 = W[tid * 4 + 0], w1 = W[tid * 4 + 1];
            float w2 = W[tid * 4 + 2], w3 = W[tid * 4 + 3];
            float bb = b[tid];
            #pragma unroll
            for (int o = 32; o > 0; o >>= 1) {
                w0 += __shfl_down(w0, o);
                w1 += __shfl_down(w1, o);
                w2 += __shfl_down(w2, o);
                w3 += __shfl_down(w3, o);
                bb += __shfl_down(bb, o);
            }
            if (tid == 0) { wsb[0] = w0; wsb[1] = w1; wsb[2] = w2; wsb[3] = w3; wsb[4] = bb; }
        }
        __syncthreads();
        int e = (blk - 2304) * 256 + tid;
        float4 a = *(const float4*)(ea + (size_t)e * 4);
        es[e] = a.x * wsb[0] + a.y * wsb[1] + a.z * wsb[2] + a.w * wsb[3] + wsb[4];
        int src = ei[e];
        int dst = ei[NEDGE + e];
        int pos = atomicAdd(&cnt[src], 1);
        if (pos < RCAP) keys[src * RCAP + pos] = (dst << 18) | e;
    }
}

// ---- per-row sort by (dst,e): one wave per row, 1 key/lane, 64-wide bitonic;
// mark all-but-last duplicate dst dead (numpy last-wins).
__global__ __launch_bounds__(256) void cpa_sortrows(const int* __restrict__ cnt,
                                                    int* __restrict__ keys) {
    int row  = blockIdx.x * 4 + (threadIdx.x >> 6);
    int lane = threadIdx.x & 63;
    int len  = min(cnt[row], RCAP);
    int base = row * RCAP;
    int v = (lane < len) ? keys[base + lane] : 0x7FFFFFFF;

    #pragma unroll
    for (int k = 2; k <= 64; k <<= 1) {
        #pragma unroll
        for (int j = k >> 1; j >= 1; j >>= 1) {
            int p = __shfl_xor(v, j);
            bool asc = (lane & k) == 0;
            bool low = (lane & j) == 0;
            v = (low == asc) ? min(v, p) : max(v, p);
        }
    }
    int nxt = __shfl_down(v, 1);
    bool dead = (lane + 1 < len) && ((v >> 18) == (nxt >> 18));
    if (lane < len) keys[base + lane] = v | (dead ? 0x80000000 : 0);
}

// ---- flash attention, 32x32x16 MFMA core (R13 structure: 512 thr, BR=128,
// SPLITS=8, 3 barriers/tile) + REGISTER PREFETCH of the staging loads: next
// tile's global data is loaded into regs right after B1 and consumed only at
// the next loop top, hiding the L2 load latency behind S+PV compute.
__global__ __launch_bounds__(512, 4) void cpa_flash(
    const short* __restrict__ Xbf, const short* __restrict__ Ybt,
    const float* __restrict__ es, const int* __restrict__ keys,
    const int* __restrict__ cnt,
    float* __restrict__ lsplit, short* __restrict__ Opart)
{
    __shared__ short Xj[BC][136];     // X tile (j rows), stride 136
    __shared__ short Yt[DX][72];      // V tile K-transposed: Yt[feature][j-local]
    __shared__ short Pl[BR][72];      // P tile

    const int tid  = threadIdx.x;
    const int lane = tid & 63;
    const int w    = tid >> 6;        // wave 0..7
    const int l31  = lane & 31;
    const int lh   = lane >> 5;       // K-half within fragment
    const int rg   = w >> 1;          // row group (32 rows), S and PV
    const int cg   = w & 1;           // S col group / P region half
    const int ocg0 = (w & 1) * 2;     // PV col-tile pair {ocg0, ocg0+1}

    const int ib = blockIdx.x;        // 0..63
    const int split = blockIdx.y;     // 0..SPLITS-1
    const int i0 = ib * BR;
    const int jstart = split * (N_NODES / SPLITS);

    // per-thread staging slots (constant across tiles)
    const int xr0 = tid >> 4,          xc0 = (tid & 15) << 3;          // Xj slot 0
    const int xr1 = (tid + 512) >> 4,  xc1 = ((tid + 512) & 15) << 3;  // Xj slot 1
    const int yn0 = tid >> 3,          yk0 = (tid & 7) << 3;           // Yt slot 0
    const int yn1 = (tid + 512) >> 3,  yk1 = ((tid + 512) & 7) << 3;   // Yt slot 1

    // Xi A-fragments: rows rg*32+l31, 8 K-chunks of 16 over 128 features (global, once)
    short8 afrag[8];
    #pragma unroll
    for (int kf = 0; kf < 8; ++kf)
        afrag[kf] = *(const short8*)(Xbf + (size_t)(i0 + rg * 32 + l31) * DX + kf * 16 + lh * 8);

    short8 ones;
    #pragma unroll
    for (int j = 0; j < 8; ++j) ones[j] = (short)0x3F80;   // bf16 1.0

    // walker cursor: lane<32 owns row i0 + rg*32 + lane
    int cur = 0, rend = 0;
    if (lane < 32) {
        int i = i0 + rg * 32 + l31;
        cur = i * RCAP;
        rend = cur + min(cnt[i], RCAP);
        while (cur < rend) {
            int k = keys[cur];
            if (((k >> 18) & 0x1FFF) >= jstart) break;
            ++cur;
        }
    }

    f32x16 O0, O1, lC;
    #pragma unroll
    for (int r = 0; r < 16; ++r) { O0[r] = 0.f; O1[r] = 0.f; lC[r] = 0.f; }

    // prefetch tile 0 into registers
    int4 xp0 = *(const int4*)(Xbf + (size_t)(jstart + xr0) * DX + xc0);
    int4 xp1 = *(const int4*)(Xbf + (size_t)(jstart + xr1) * DX + xc1);
    int4 yp0 = *(const int4*)(Ybt + (size_t)yn0 * N_NODES + jstart + yk0);
    int4 yp1 = *(const int4*)(Ybt + (size_t)yn1 * N_NODES + jstart + yk1);

    for (int tt = 0; tt < TILES; ++tt) {
        const int j0 = jstart + tt * BC;
        // phase A: commit prefetched registers to LDS
        *(int4*)(&Xj[xr0][xc0]) = xp0;
        *(int4*)(&Xj[xr1][xc1]) = xp1;
        *(int4*)(&Yt[yn0][yk0]) = yp0;
        *(int4*)(&Yt[yn1][yk1]) = yp1;
        __syncthreads();  // B1: staging visible

        // issue next tile's global loads (consumed at next loop top -> latency
        // hidden behind this tile's S + PV compute)
        {
            const int jn = (tt + 1 < TILES) ? (j0 + BC) : j0;   // last iter: dummy reload
            xp0 = *(const int4*)(Xbf + (size_t)(jn + xr0) * DX + xc0);
            xp1 = *(const int4*)(Xbf + (size_t)(jn + xr1) * DX + xc1);
            yp0 = *(const int4*)(Ybt + (size_t)yn0 * N_NODES + jn + yk0);
            yp1 = *(const int4*)(Ybt + (size_t)yn1 * N_NODES + jn + yk1);
        }

        // phase B: S (32x32) = Xi(rg) · Xj(cg)^T, 8 K-steps
        f32x16 S;
        #pragma unroll
        for (int r = 0; r < 16; ++r) S[r] = 0.f;
        #pragma unroll
        for (int kf = 0; kf < 8; ++kf) {
            short8 bfrag = *(const short8*)&Xj[cg * 32 + l31][kf * 16 + lh * 8];
            S = __builtin_amdgcn_mfma_f32_32x32x16_bf16(afrag[kf], bfrag, S, 0, 0, 0);
        }
        // p = exp(S - 66) -> own Pl region (row rg*32+rowl, col cg*32+l31)
        #pragma unroll
        for (int r = 0; r < 16; ++r) {
            int rowl = 4 * lh + (r & 3) + 8 * (r >> 2);
            Pl[rg * 32 + rowl][cg * 32 + l31] = f2bf(__expf(S[r] - MSHIFT));
        }
        // bias RMW on own region (same-wave DS ordering; lanes 0..31)
        if (lane < 32) {
            const int jend = j0 + BC;
            const int wlo = j0 + cg * 32;
            int c = cur;
            while (c < rend) {
                int k = keys[c];
                int dst = (k >> 18) & 0x1FFF;
                if (dst >= jend) break;
                ++c;
                if (k >= 0) {
                    unsigned cl = (unsigned)(dst - wlo);
                    if (cl < 32u) {
                        short* p = &Pl[rg * 32 + l31][cg * 32 + (int)cl];
                        *p = f2bf(bf2f(*p) * __expf(es[k & 0x3FFFF]));
                    }
                }
            }
            cur = c;
        }
        __syncthreads();  // B2: biased P visible to all waves

        // phase D: O += P·Y (2 col tiles sharing A-frags); l += P·1 (even waves)
        #pragma unroll
        for (int ks = 0; ks < 4; ++ks) {
            short8 pa  = *(const short8*)&Pl[rg * 32 + l31][ks * 16 + lh * 8];
            short8 yb0 = *(const short8*)&Yt[ocg0 * 32 + l31][ks * 16 + lh * 8];
            short8 yb1 = *(const short8*)&Yt[(ocg0 + 1) * 32 + l31][ks * 16 + lh * 8];
            O0 = __builtin_amdgcn_mfma_f32_32x32x16_bf16(pa, yb0, O0, 0, 0, 0);
            O1 = __builtin_amdgcn_mfma_f32_32x32x16_bf16(pa, yb1, O1, 0, 0, 0);
            if (!(w & 1))
                lC = __builtin_amdgcn_mfma_f32_32x32x16_bf16(pa, ones, lC, 0, 0, 0);
        }
        __syncthreads();  // B4: WAR before next staging / P-store
    }

    // epilogue: O (bf16) and l (fixed shift => merge is a plain sum)
    #pragma unroll
    for (int r = 0; r < 16; ++r) {
        int row = rg * 32 + 4 * lh + (r & 3) + 8 * (r >> 2);
        size_t base = ((size_t)split * N_NODES + i0 + row) * DX;
        Opart[base + ocg0 * 32 + l31]       = f2bf(O0[r]);
        Opart[base + (ocg0 + 1) * 32 + l31] = f2bf(O1[r]);
    }
    if (!(w & 1) && l31 == 0) {
        #pragma unroll
        for (int r = 0; r < 16; ++r) {
            int row = rg * 32 + 4 * lh + (r & 3) + 8 * (r >> 2);
            lsplit[(size_t)split * N_NODES + i0 + row] = lC[r];
        }
    }
}

// ---- merge splits (plain sums) + normalize + write [new_mag | new_phase]
__global__ void cpa_merge(const float* __restrict__ lsplit, const short* __restrict__ Opart,
                          float* __restrict__ out) {
    int gid = blockIdx.x * 256 + threadIdx.x;   // N*128 threads
    int i = gid >> 7;
    int c = gid & 127;
    float den = 0.f, num = 0.f;
    #pragma unroll
    for (int s = 0; s < SPLITS; ++s) {
        den += lsplit[(size_t)s * N_NODES + i];
        num += bf2f(Opart[((size_t)s * N_NODES + i) * DX + c]);
    }
    float val = num / den;
    if (c < 64) out[(size_t)i * 64 + c] = val;
    else        out[(size_t)N_NODES * 64 + (size_t)i * 64 + (c - 64)] = val;
}

extern "C" void kernel_launch(void* const* d_in, const int* in_sizes, int n_in,
                              void* d_out, int out_size, void* d_ws, size_t ws_size,
                              hipStream_t stream)
{
    const float* mag   = (const float*)d_in[0];
    const float* phase = (const float*)d_in[1];
    const int*   ei    = (const int*)d_in[2];     // edge_index [2][E] (int32 per harness)
    const float* ea    = (const float*)d_in[3];
    const float* W     = (const float*)d_in[4];
    const float* b     = (const float*)d_in[5];
    float* out = (float*)d_out;

    char* ws = (char*)d_ws;
    short* Xbf    = (short*)(ws + 0);               // 2 MB
    short* Ybt    = (short*)(ws + 2097152);         // 2 MB
    float* es     = (float*)(ws + 4194304);         // 1 MB
    int*   keys   = (int*)  (ws + 5242880);         // 2 MB (8192 rows x 64 bins)
    int*   cnt    = (int*)  (ws + 7340032);         // 32 KB
    float* lsplit = (float*)(ws + 7373056);         // 256 KB (8 splits)
    short* Opart  = (short*)(ws + 7635200);         // 16 MB (bf16, 8 splits)

    hipMemsetAsync(cnt, 0, N_NODES * sizeof(int), stream);
    cpa_prep_all<<<2048 + 256 + NEDGE / 256, 256, 0, stream>>>(mag, phase, ei, ea, W, b,
                                                               Xbf, Ybt, es, cnt, keys);
    cpa_sortrows<<<N_NODES / 4, 256, 0, stream>>>(cnt, keys);
    cpa_flash<<<dim3(N_NODES / BR, SPLITS), 512, 0, stream>>>(Xbf, Ybt, es, keys, cnt,
                                                              lsplit, Opart);
    cpa_merge<<<N_NODES * DX / 256, 256, 0, stream>>>(lsplit, Opart, out);
}